// Round 6
// baseline (276.534 us; speedup 1.0000x reference)
//
#include <hip/hip_runtime.h>
#include <stdint.h>

typedef __attribute__((ext_vector_type(8))) short short8;
typedef __attribute__((ext_vector_type(4))) float f32x4;

#define MFMA(A, B, C) __builtin_amdgcn_mfma_f32_16x16x32_bf16(A, B, C, 0, 0, 0)

__device__ inline void split_trunc(float f, short& hi, short& lo) {
  uint32_t u = __float_as_uint(f);
  hi = (short)(u >> 16);
  float r = f - __uint_as_float(u & 0xffff0000u);
  lo = (short)(__float_as_uint(r) >> 16);
}

__device__ inline uint32_t cvtpk(float a, float b) {  // D = {bf16(b):bf16(a)}
  uint32_t r;
  asm("v_cvt_pk_bf16_f32 %0, %1, %2" : "=v"(r) : "v"(a), "v"(b));
  return r;
}

__device__ inline void gload16(const short* g, short* l) {
  __builtin_amdgcn_global_load_lds(
      (const __attribute__((address_space(1))) void*)g,
      (__attribute__((address_space(3))) void*)l, 16, 0, 0);
}

// ---------- prep kernels ----------

__global__ void split_x_kernel(const float* __restrict__ x, short* __restrict__ hi,
                               short* __restrict__ lo) {
  int t = blockIdx.x * 256 + threadIdx.x;
  float4 v0 = *(const float4*)&x[(size_t)t * 8];
  float4 v1 = *(const float4*)&x[(size_t)t * 8 + 4];
  float buf[8] = {v0.x, v0.y, v0.z, v0.w, v1.x, v1.y, v1.z, v1.w};
  short8 h, l;
#pragma unroll
  for (int i = 0; i < 8; ++i) { short a, b; split_trunc(buf[i], a, b); h[i] = a; l[i] = b; }
  *(short8*)&hi[(size_t)t * 8] = h;
  *(short8*)&lo[(size_t)t * 8] = l;
}

// fused weight prep: [0,4096) wct split; [4096,4608) kv_w T; [4608,4864) q_w T; [4864,5120) proj_w T
__global__ __launch_bounds__(256) void prep_weights_kernel(
    const float* __restrict__ sr_w, const float* __restrict__ kv_w,
    const float* __restrict__ q_w, const float* __restrict__ proj_w,
    short* __restrict__ WcThi, short* __restrict__ WcTlo,
    short* __restrict__ kvThi, short* __restrict__ kvTlo,
    short* __restrict__ qThi, short* __restrict__ qTlo,
    short* __restrict__ pThi, short* __restrict__ pTlo) {
  __shared__ float tile[32][33];
  const int blk = blockIdx.x;
  if (blk < 4096) {
    int t = blk * 256 + threadIdx.x;
    int kk = t & 2047, o = t >> 11;
    float v = sr_w[(size_t)o * 2048 + ((kk & 511) << 2) + (kk >> 9)];
    short a, b; split_trunc(v, a, b);
    WcThi[t] = a; WcTlo[t] = b;
    return;
  }
  const float* in; short* ohi; short* olo; int N, bx, by;
  if (blk < 4608) {
    in = kv_w; ohi = kvThi; olo = kvTlo; N = 1024;
    int i = blk - 4096; bx = i & 31; by = i >> 5;
  } else if (blk < 4864) {
    in = q_w; ohi = qThi; olo = qTlo; N = 512;
    int i = blk - 4608; bx = i & 15; by = i >> 4;
  } else {
    in = proj_w; ohi = pThi; olo = pTlo; N = 512;
    int i = blk - 4864; bx = i & 15; by = i >> 4;
  }
  const int K = 512;
  const int tx = threadIdx.x & 31, ty = threadIdx.x >> 5;
#pragma unroll
  for (int i = 0; i < 4; ++i)
    tile[ty + i * 8][tx] = in[(size_t)(by * 32 + ty + i * 8) * N + bx * 32 + tx];
  __syncthreads();
#pragma unroll
  for (int i = 0; i < 4; ++i) {
    int n = bx * 32 + ty + i * 8;
    float v = tile[tx][ty + i * 8];
    short a, b; split_trunc(v, a, b);
    size_t idx = (size_t)n * K + by * 32 + tx;
    ohi[idx] = a; olo[idx] = b;
  }
}

__global__ __launch_bounds__(256) void ln_split_kernel(
    const float* __restrict__ X, const float* __restrict__ g,
    const float* __restrict__ bta, short* __restrict__ hi, short* __restrict__ lo) {
  const int row = blockIdx.x, t = threadIdx.x;
  size_t idx = (size_t)row * 512 + t * 2;
  const size_t PS = (size_t)2048 * 512;
  float2 a0 = *(const float2*)&X[idx];
  float2 a1 = *(const float2*)&X[idx + PS];
  float2 a2 = *(const float2*)&X[idx + 2 * PS];
  float2 a3 = *(const float2*)&X[idx + 3 * PS];
  float x0 = a0.x + a1.x + a2.x + a3.x;
  float x1 = a0.y + a1.y + a2.y + a3.y;
  float s = x0 + x1, sq = x0 * x0 + x1 * x1;
#pragma unroll
  for (int off = 1; off < 64; off <<= 1) {
    s += __shfl_xor(s, off);
    sq += __shfl_xor(sq, off);
  }
  __shared__ float rs[4], rq[4];
  int wid = t >> 6;
  if ((t & 63) == 0) { rs[wid] = s; rq[wid] = sq; }
  __syncthreads();
  s = rs[0] + rs[1] + rs[2] + rs[3];
  sq = rq[0] + rq[1] + rq[2] + rq[3];
  float mu = s * (1.f / 512), var = sq * (1.f / 512) - mu * mu;
  float inv = rsqrtf(var + 1e-5f);
  float2 gg = *(const float2*)&g[t * 2], bb = *(const float2*)&bta[t * 2];
  float o0 = (x0 - mu) * inv * gg.x + bb.x;
  float o1 = (x1 - mu) * inv * gg.y + bb.y;
  short h0, l0, h1, l1;
  split_trunc(o0, h0, l0);
  split_trunc(o1, h1, l1);
  *(uint32_t*)&hi[idx] = (uint32_t)(uint16_t)h0 | ((uint32_t)(uint16_t)h1 << 16);
  *(uint32_t*)&lo[idx] = (uint32_t)(uint16_t)l0 | ((uint32_t)(uint16_t)l1 << 16);
}

// fused KV post: [0,4096) K trunc-split [b][m][d]; [4096,8192) V -> VT bf16 [b][d][m]
__global__ void kv_post_kernel(const float* __restrict__ KV1, const float* __restrict__ KV2,
                               short* __restrict__ khi, short* __restrict__ klo,
                               short* __restrict__ vt) {
  const int blk = blockIdx.x;
  if (blk < 4096) {
    int t = blk * 256 + threadIdx.x;
    int b = t >> 17, i = t & 131071;
    size_t idx = ((size_t)b * 256 + (i >> 9)) * 1024 + (i & 511);
    float v = KV1[idx] + KV2[idx];
    short a, c; split_trunc(v, a, c);
    khi[t] = a; klo[t] = c;
  } else {
    int t = (blk - 4096) * 256 + threadIdx.x;
    int b = t >> 17, i = t & 131071;
    int d = i >> 11, m = i & 2047;
    size_t idx = ((size_t)b * 256 + (m >> 3)) * 1024 + 512 + (m & 7) * 64 + d;
    float v = KV1[idx] + KV2[idx];
    uint32_t u = __float_as_uint(v);
    vt[t] = (short)((u + 0x7FFFu + ((u >> 16) & 1u)) >> 16);
  }
}

// ---------- bf16x3 GEMM: 64x128 tile, 4 waves, BK=64 (one barrier-pair per 64 k) ----------
template <bool GATHER, int OMODE>
__global__ __launch_bounds__(256) void gemm_x3(
    const short* __restrict__ Ahi, const short* __restrict__ Alo,
    const short* __restrict__ BThi, const short* __restrict__ BTlo,
    const float* __restrict__ bias, float* __restrict__ C,
    short* __restrict__ Chi, short* __restrict__ Clo, float oscale,
    int M, int N, int lda, int ldb, int klen) {
  __shared__ short ldsA[2][8][64][8];    // 16KB
  __shared__ short ldsB[2][8][128][8];   // 32KB
  const int tid = threadIdx.x, lane = tid & 63, wave = tid >> 6;
  const int g = lane >> 4, qi = lane & 15;
  const int row0 = blockIdx.x * 64, col0 = blockIdx.y * 128;
  const int kz = blockIdx.z * klen;
  float* Cz = C + (size_t)blockIdx.z * M * N;
  const bool dobias = (blockIdx.z == 0);
  f32x4 acc[4][2] = {};

  for (int k0 = kz; k0 < kz + klen; k0 += 64) {
    __syncthreads();
#pragma unroll
    for (int r = 0; r < 2; ++r) {
      int idx = tid + r * 256;
      int arow = idx & 63, akg = idx >> 6;   // 64 rows x 8 kg
      size_t ao;
      if (GATHER) {
        int row = row0 + arow;
        int bi = row >> 8, p = row & 255;
        int col = k0 + akg * 8;
        int seg = col >> 9, cc = col & 511;
        int n = (2 * (p >> 4) + (seg >> 1)) * 32 + 2 * (p & 15) + (seg & 1);
        ao = ((size_t)bi * 1024 + n) * 512 + cc;
      } else {
        ao = (size_t)(row0 + arow) * lda + k0 + akg * 8;
      }
      gload16(&Ahi[ao], &ldsA[0][akg][arow][0]);
      gload16(&Alo[ao], &ldsA[1][akg][arow][0]);
    }
#pragma unroll
    for (int r = 0; r < 4; ++r) {
      int idx = tid + r * 256;
      int bcol = idx & 127, bkg = idx >> 7;  // 128 cols x 8 kg
      size_t bo = (size_t)(col0 + bcol) * ldb + k0 + bkg * 8;
      gload16(&BThi[bo], &ldsB[0][bkg][bcol][0]);
      gload16(&BTlo[bo], &ldsB[1][bkg][bcol][0]);
    }
    __syncthreads();
#pragma unroll
    for (int kk = 0; kk < 2; ++kk) {
      const int kg = kk * 4 + g;
      short8 ah[4], al[4], bh[2], bl[2];
#pragma unroll
      for (int i = 0; i < 4; ++i) {
        ah[i] = *(const short8*)&ldsA[0][kg][i * 16 + qi][0];
        al[i] = *(const short8*)&ldsA[1][kg][i * 16 + qi][0];
      }
#pragma unroll
      for (int j = 0; j < 2; ++j) {
        bh[j] = *(const short8*)&ldsB[0][kg][wave * 32 + j * 16 + qi][0];
        bl[j] = *(const short8*)&ldsB[1][kg][wave * 32 + j * 16 + qi][0];
      }
#pragma unroll
      for (int i = 0; i < 4; ++i)
#pragma unroll
        for (int j = 0; j < 2; ++j) {
          acc[i][j] = MFMA(ah[i], bh[j], acc[i][j]);
          acc[i][j] = MFMA(al[i], bh[j], acc[i][j]);
          acc[i][j] = MFMA(ah[i], bl[j], acc[i][j]);
        }
    }
  }
#pragma unroll
  for (int i = 0; i < 4; ++i)
#pragma unroll
    for (int j = 0; j < 2; ++j) {
      int colb = col0 + wave * 32 + j * 16 + qi;
      float bs = dobias ? bias[colb] : 0.f;
#pragma unroll
      for (int r = 0; r < 4; ++r) {
        int row = row0 + i * 16 + g * 4 + r;
        if (OMODE == 0) {
          Cz[(size_t)row * N + colb] = acc[i][j][r] + bs;
        } else {
          float v = (acc[i][j][r] + bs) * oscale;
          short hh, ll;
          split_trunc(v, hh, ll);
          Chi[(size_t)row * N + colb] = hh;
          Clo[(size_t)row * N + colb] = ll;
        }
      }
    }
}

// ---------- MFMA flash attention: 32 q/wave, K dbuf-LDS, V reg-prefetch, exp2 domain ----------
__global__ __launch_bounds__(256, 2) void attn_kernel(
    const short* __restrict__ Qhi, const short* __restrict__ Qlo,
    const short* __restrict__ Khi, const short* __restrict__ Klo,
    const short* __restrict__ VT, short* __restrict__ Ohi, short* __restrict__ Olo) {
  __shared__ short Ks[2][2][4096];      // [dbuf][hi/lo][64x64 swizzled] 32KB
  __shared__ short Ps[4][2][2][1024];   // [wave][qc][hi/lo] 32KB
  const int tid = threadIdx.x, lane = tid & 63, wave = tid >> 6;
  const int g = lane >> 4, qi = lane & 15;
  const int h = blockIdx.y, b = blockIdx.z;
  const int n0 = blockIdx.x * 128 + wave * 32;

  // Q frags pre-split & pre-scaled by (0.125*log2e) in the Q-GEMM epilogue
  short8 qh[2][2], ql[2][2];   // [qc][ks]
#pragma unroll
  for (int qc = 0; qc < 2; ++qc) {
    const size_t qrow = ((size_t)b * 1024 + n0 + qc * 16 + qi) * 512 + h * 64;
#pragma unroll
    for (int ks = 0; ks < 2; ++ks) {
      qh[qc][ks] = *(const short8*)&Qhi[qrow + (ks * 4 + g) * 8];
      ql[qc][ks] = *(const short8*)&Qlo[qrow + (ks * 4 + g) * 8];
    }
  }
  float m_run = 0.f, l_run[2] = {0.f, 0.f};
  f32x4 oacc[2][4] = {};
  const short* Kh = Khi + (size_t)b * 2048 * 64;
  const short* Kl = Klo + (size_t)b * 2048 * 64;
  const short* Vb = VT + (size_t)b * 64 * 2048;
  const int swz = (qi & 7) << 1;
  const int srow = tid >> 3, sch = tid & 7;
  const int ssw = (sch * 16) ^ ((srow & 7) << 4);
  const int srow2 = (256 + tid) >> 3, ssw2 = (sch * 16) ^ ((srow2 & 7) << 4);

  gload16((const short*)((const char*)Kh + (size_t)srow * 128 + ssw), &Ks[0][0][tid * 8]);
  gload16((const short*)((const char*)Kl + (size_t)srow * 128 + ssw), &Ks[0][1][tid * 8]);
  gload16((const short*)((const char*)Kh + (size_t)srow2 * 128 + ssw2), &Ks[0][0][(256 + tid) * 8]);
  gload16((const short*)((const char*)Kl + (size_t)srow2 * 128 + ssw2), &Ks[0][1][(256 + tid) * 8]);
  __syncthreads();
  int bb = 0;

  for (int t = 0; t < 32; ++t) {
    const int m0 = t * 64;
    if (t < 31) {
      const size_t g1 = (size_t)(m0 + 64 + srow) * 128;
      const size_t g2 = (size_t)(m0 + 64 + srow2) * 128;
      gload16((const short*)((const char*)Kh + g1 + ssw), &Ks[bb ^ 1][0][tid * 8]);
      gload16((const short*)((const char*)Kl + g1 + ssw), &Ks[bb ^ 1][1][tid * 8]);
      gload16((const short*)((const char*)Kh + g2 + ssw2), &Ks[bb ^ 1][0][(256 + tid) * 8]);
      gload16((const short*)((const char*)Kl + g2 + ssw2), &Ks[bb ^ 1][1][(256 + tid) * 8]);
    }
    short8 vreg[8];
#pragma unroll
    for (int ks2 = 0; ks2 < 2; ++ks2)
#pragma unroll
      for (int df = 0; df < 4; ++df)
        vreg[ks2 * 4 + df] =
            *(const short8*)&Vb[(size_t)(df * 16 + qi) * 2048 + m0 + ks2 * 32 + g * 8];
    // QK^T swapped (S^T in log2 domain), both q-columns share K frags
    f32x4 s[2][4] = {};
    const int c0 = 8 * (g ^ (qi & 7)), c1 = 8 * ((g + 4) ^ (qi & 7));
#pragma unroll
    for (int mf = 0; mf < 4; ++mf) {
      const int rowb = (mf * 16 + qi) * 64;
      short8 kh0 = *(const short8*)&Ks[bb][0][rowb + c0];
      short8 kl0 = *(const short8*)&Ks[bb][1][rowb + c0];
      short8 kh1 = *(const short8*)&Ks[bb][0][rowb + c1];
      short8 kl1 = *(const short8*)&Ks[bb][1][rowb + c1];
#pragma unroll
      for (int qc = 0; qc < 2; ++qc) {
        s[qc][mf] = MFMA(kh0, qh[qc][0], s[qc][mf]);
        s[qc][mf] = MFMA(kl0, qh[qc][0], s[qc][mf]);
        s[qc][mf] = MFMA(kh0, ql[qc][0], s[qc][mf]);
        s[qc][mf] = MFMA(kh1, qh[qc][1], s[qc][mf]);
        s[qc][mf] = MFMA(kl1, qh[qc][1], s[qc][mf]);
        s[qc][mf] = MFMA(kh1, ql[qc][1], s[qc][mf]);
      }
    }
    // defer-max online softmax (log2 units)
    float lmax = s[0][0][0];
#pragma unroll
    for (int qc = 0; qc < 2; ++qc)
#pragma unroll
      for (int mf = 0; mf < 4; ++mf)
#pragma unroll
        for (int r = 0; r < 4; ++r) lmax = fmaxf(lmax, s[qc][mf][r]);
    if (!__all(lmax <= m_run + 43.f)) {
      float mx = lmax;
#pragma unroll
      for (int off = 1; off < 64; off <<= 1) mx = fmaxf(mx, __shfl_xor(mx, off));
      float cf = exp2f(m_run - mx);
      l_run[0] *= cf; l_run[1] *= cf;
#pragma unroll
      for (int qc = 0; qc < 2; ++qc)
#pragma unroll
        for (int df = 0; df < 4; ++df) oacc[qc][df] *= cf;
      m_run = mx;
    }
#pragma unroll
    for (int qc = 0; qc < 2; ++qc) {
      float lsum = 0.f;
#pragma unroll
      for (int mf = 0; mf < 4; ++mf)
#pragma unroll
        for (int r = 0; r < 4; ++r) {
          float p = exp2f(s[qc][mf][r] - m_run);
          s[qc][mf][r] = p;
          lsum += p;
        }
      lsum += __shfl_xor(lsum, 16);
      lsum += __shfl_xor(lsum, 32);
      l_run[qc] += lsum;
    }
    // pack P hi(RNE)/lo via v_cvt_pk_bf16_f32 -> per-wave-per-qc LDS bounce, then PV
#pragma unroll
    for (int qc = 0; qc < 2; ++qc) {
#pragma unroll
      for (int mf = 0; mf < 4; ++mf) {
        uint32_t h01 = cvtpk(s[qc][mf][0], s[qc][mf][1]);
        uint32_t h23 = cvtpk(s[qc][mf][2], s[qc][mf][3]);
        float l0 = s[qc][mf][0] - __uint_as_float(h01 << 16);
        float l1 = s[qc][mf][1] - __uint_as_float(h01 & 0xffff0000u);
        float l2 = s[qc][mf][2] - __uint_as_float(h23 << 16);
        float l3 = s[qc][mf][3] - __uint_as_float(h23 & 0xffff0000u);
        uint2 hp, lp;
        hp.x = h01; hp.y = h23;
        lp.x = cvtpk(l0, l1); lp.y = cvtpk(l2, l3);
        int uw = ((mf * 4 + g) ^ swz) << 2;
        *(uint2*)&Ps[wave][qc][0][qi * 64 + uw] = hp;
        *(uint2*)&Ps[wave][qc][1][qi * 64 + uw] = lp;
      }
#pragma unroll
      for (int ks2 = 0; ks2 < 2; ++ks2) {
        int ur = ((ks2 * 8 + g * 2) ^ swz) << 2;
        short8 pa = *(const short8*)&Ps[wave][qc][0][qi * 64 + ur];
        short8 pl = *(const short8*)&Ps[wave][qc][1][qi * 64 + ur];
#pragma unroll
        for (int df = 0; df < 4; ++df) {
          oacc[qc][df] = MFMA(vreg[ks2 * 4 + df], pa, oacc[qc][df]);
          oacc[qc][df] = MFMA(vreg[ks2 * 4 + df], pl, oacc[qc][df]);
        }
      }
    }
    __syncthreads();
    bb ^= 1;
  }
#pragma unroll
  for (int qc = 0; qc < 2; ++qc) {
    float linv = 1.f / l_run[qc];
    size_t obase = ((size_t)b * 1024 + n0 + qc * 16 + qi) * 512 + h * 64;
#pragma unroll
    for (int df = 0; df < 4; ++df) {
      float o0 = oacc[qc][df][0] * linv, o1 = oacc[qc][df][1] * linv;
      float o2 = oacc[qc][df][2] * linv, o3 = oacc[qc][df][3] * linv;
      uint32_t h01 = cvtpk(o0, o1);
      uint32_t h23 = cvtpk(o2, o3);
      float l0 = o0 - __uint_as_float(h01 << 16);
      float l1 = o1 - __uint_as_float(h01 & 0xffff0000u);
      float l2 = o2 - __uint_as_float(h23 << 16);
      float l3 = o3 - __uint_as_float(h23 & 0xffff0000u);
      uint2 hp, lp;
      hp.x = h01; hp.y = h23;
      lp.x = cvtpk(l0, l1); lp.y = cvtpk(l2, l3);
      *(uint2*)&Ohi[obase + df * 16 + g * 4] = hp;
      *(uint2*)&Olo[obase + df * 16 + g * 4] = lp;
    }
  }
}

// ---------- launcher ----------
extern "C" void kernel_launch(void* const* d_in, const int* in_sizes, int n_in,
                              void* d_out, int out_size, void* d_ws, size_t ws_size,
                              hipStream_t stream) {
  const float* x      = (const float*)d_in[0];
  const float* q_w    = (const float*)d_in[3];
  const float* q_b    = (const float*)d_in[4];
  const float* kv_w   = (const float*)d_in[5];
  const float* kv_b   = (const float*)d_in[6];
  const float* sr_w   = (const float*)d_in[7];
  const float* sr_b   = (const float*)d_in[8];
  const float* ln_g   = (const float*)d_in[9];
  const float* ln_b   = (const float*)d_in[10];
  const float* proj_w = (const float*)d_in[11];
  const float* proj_b = (const float*)d_in[12];

  char* W = (char*)d_ws;
  const size_t MB = 1024 * 1024;
  short* xhi   = (short*)(W);                  // 0-8
  short* xlo   = (short*)(W + 8 * MB);         // 8-16
  short* WcThi = (short*)(W + 16 * MB);        // 16-18
  short* WcTlo = (short*)(W + 18 * MB);        // 18-20
  float* Cbuf  = (float*)(W + 20 * MB);        // 20-36 (4 partials x 4MB)
  short* LNhi  = (short*)(W + 36 * MB);        // 36-38
  short* LNlo  = (short*)(W + 38 * MB);        // 38-40
  short* kvThi = (short*)(W + 40 * MB);        // 40-41
  short* kvTlo = (short*)(W + 41 * MB);        // 41-42
  short* qThi  = (short*)(W + 42 * MB);        // 42-42.5
  short* qTlo  = (short*)(W + 42 * MB + MB / 2);
  short* pThi  = (short*)(W + 43 * MB);        // 43-43.5
  short* pTlo  = (short*)(W + 43 * MB + MB / 2);
  float* KVp   = (float*)(W + 20 * MB);        // 20-36 (Cbuf dead)
  short* Khi   = (short*)(W + 36 * MB);        // 36-38 (LN dead)
  short* Klo   = (short*)(W + 38 * MB);        // 38-40
  short* VTb   = (short*)(W + 16 * MB);        // 16-18 (WcT dead)
  short* Qhi   = (short*)(W + 20 * MB);        // 20-28 (KVp dead)
  short* Qlo   = (short*)(W + 28 * MB);        // 28-36
  short* Ohi   = (short*)(W);                  // 0-8  (x dead after Q-GEMM)
  short* Olo   = (short*)(W + 8 * MB);         // 8-16

  prep_weights_kernel<<<5120, 256, 0, stream>>>(
      sr_w, kv_w, q_w, proj_w, WcThi, WcTlo, kvThi, kvTlo, qThi, qTlo, pThi, pTlo);
  split_x_kernel<<<2048, 256, 0, stream>>>(x, xhi, xlo);
  gemm_x3<true, 0><<<dim3(32, 4, 4), 256, 0, stream>>>(
      xhi, xlo, WcThi, WcTlo, sr_b, Cbuf, nullptr, nullptr, 1.f,
      2048, 512, 512, 2048, 512);
  ln_split_kernel<<<2048, 256, 0, stream>>>(Cbuf, ln_g, ln_b, LNhi, LNlo);
  gemm_x3<false, 0><<<dim3(32, 8, 2), 256, 0, stream>>>(
      LNhi, LNlo, kvThi, kvTlo, kv_b, KVp, nullptr, nullptr, 1.f,
      2048, 1024, 512, 512, 256);
  kv_post_kernel<<<8192, 256, 0, stream>>>(KVp, KVp + (size_t)2 * MB, Khi, Klo, VTb);
  gemm_x3<false, 1><<<dim3(128, 4, 1), 256, 0, stream>>>(
      xhi, xlo, qThi, qTlo, q_b, nullptr, Qhi, Qlo, 0.125f * 1.44269504f,
      8192, 512, 512, 512, 512);
  attn_kernel<<<dim3(8, 8, 8), 256, 0, stream>>>(Qhi, Qlo, Khi, Klo, VTb, Ohi, Olo);
  gemm_x3<false, 0><<<dim3(128, 4, 1), 256, 0, stream>>>(
      Ohi, Olo, pThi, pTlo, proj_b, (float*)d_out, nullptr, nullptr, 1.f,
      8192, 512, 512, 512, 512);
}

// Round 7
// 204.485 us; speedup vs baseline: 1.3523x; 1.3523x over previous
//
#include <hip/hip_runtime.h>
#include <stdint.h>

typedef __attribute__((ext_vector_type(8))) short short8;
typedef __attribute__((ext_vector_type(4))) float f32x4;

#define MFMA(A, B, C) __builtin_amdgcn_mfma_f32_16x16x32_bf16(A, B, C, 0, 0, 0)

__device__ inline void split_trunc(float f, short& hi, short& lo) {
  uint32_t u = __float_as_uint(f);
  hi = (short)(u >> 16);
  float r = f - __uint_as_float(u & 0xffff0000u);
  lo = (short)(__float_as_uint(r) >> 16);
}

__device__ inline uint32_t bfrne(float f) {   // RNE bf16, as low 16 bits
  uint32_t u = __float_as_uint(f);
  return (u + 0x7FFFu + ((u >> 16) & 1u)) >> 16;
}

__device__ inline void gload16(const short* g, short* l) {
  __builtin_amdgcn_global_load_lds(
      (const __attribute__((address_space(1))) void*)g,
      (__attribute__((address_space(3))) void*)l, 16, 0, 0);
}

// ---------- prep kernels ----------

__global__ void split_x_kernel(const float* __restrict__ x, short* __restrict__ hi,
                               short* __restrict__ lo) {
  int t = blockIdx.x * 256 + threadIdx.x;
  float4 v0 = *(const float4*)&x[(size_t)t * 8];
  float4 v1 = *(const float4*)&x[(size_t)t * 8 + 4];
  float buf[8] = {v0.x, v0.y, v0.z, v0.w, v1.x, v1.y, v1.z, v1.w};
  short8 h, l;
#pragma unroll
  for (int i = 0; i < 8; ++i) { short a, b; split_trunc(buf[i], a, b); h[i] = a; l[i] = b; }
  *(short8*)&hi[(size_t)t * 8] = h;
  *(short8*)&lo[(size_t)t * 8] = l;
}

// fused weight prep: [0,4096) wct split; [4096,4608) kv_w T split; [4608,4864) q_w T rne; [4864,5120) proj_w T rne
__global__ __launch_bounds__(256) void prep_weights_kernel(
    const float* __restrict__ sr_w, const float* __restrict__ kv_w,
    const float* __restrict__ q_w, const float* __restrict__ proj_w,
    short* __restrict__ WcThi, short* __restrict__ WcTlo,
    short* __restrict__ kvThi, short* __restrict__ kvTlo,
    short* __restrict__ qThi, short* __restrict__ pThi) {
  __shared__ float tile[32][33];
  const int blk = blockIdx.x;
  if (blk < 4096) {
    int t = blk * 256 + threadIdx.x;
    int kk = t & 2047, o = t >> 11;
    float v = sr_w[(size_t)o * 2048 + ((kk & 511) << 2) + (kk >> 9)];
    short a, b; split_trunc(v, a, b);
    WcThi[t] = a; WcTlo[t] = b;
    return;
  }
  const float* in; short* ohi; short* olo; int N, bx, by; bool dosplit;
  if (blk < 4608) {
    in = kv_w; ohi = kvThi; olo = kvTlo; N = 1024; dosplit = true;
    int i = blk - 4096; bx = i & 31; by = i >> 5;
  } else if (blk < 4864) {
    in = q_w; ohi = qThi; olo = nullptr; N = 512; dosplit = false;
    int i = blk - 4608; bx = i & 15; by = i >> 4;
  } else {
    in = proj_w; ohi = pThi; olo = nullptr; N = 512; dosplit = false;
    int i = blk - 4864; bx = i & 15; by = i >> 4;
  }
  const int K = 512;
  const int tx = threadIdx.x & 31, ty = threadIdx.x >> 5;
#pragma unroll
  for (int i = 0; i < 4; ++i)
    tile[ty + i * 8][tx] = in[(size_t)(by * 32 + ty + i * 8) * N + bx * 32 + tx];
  __syncthreads();
#pragma unroll
  for (int i = 0; i < 4; ++i) {
    int n = bx * 32 + ty + i * 8;
    float v = tile[tx][ty + i * 8];
    size_t idx = (size_t)n * K + by * 32 + tx;
    if (dosplit) {
      short a, b; split_trunc(v, a, b);
      ohi[idx] = a; olo[idx] = b;
    } else {
      ohi[idx] = (short)bfrne(v);
    }
  }
}

__global__ __launch_bounds__(256) void ln_split_kernel(
    const float* __restrict__ X, const float* __restrict__ g,
    const float* __restrict__ bta, short* __restrict__ hi, short* __restrict__ lo) {
  const int row = blockIdx.x, t = threadIdx.x;
  size_t idx = (size_t)row * 512 + t * 2;
  const size_t PS = (size_t)2048 * 512;
  float2 a0 = *(const float2*)&X[idx];
  float2 a1 = *(const float2*)&X[idx + PS];
  float2 a2 = *(const float2*)&X[idx + 2 * PS];
  float2 a3 = *(const float2*)&X[idx + 3 * PS];
  float x0 = a0.x + a1.x + a2.x + a3.x;
  float x1 = a0.y + a1.y + a2.y + a3.y;
  float s = x0 + x1, sq = x0 * x0 + x1 * x1;
#pragma unroll
  for (int off = 1; off < 64; off <<= 1) {
    s += __shfl_xor(s, off);
    sq += __shfl_xor(sq, off);
  }
  __shared__ float rs[4], rq[4];
  int wid = t >> 6;
  if ((t & 63) == 0) { rs[wid] = s; rq[wid] = sq; }
  __syncthreads();
  s = rs[0] + rs[1] + rs[2] + rs[3];
  sq = rq[0] + rq[1] + rq[2] + rq[3];
  float mu = s * (1.f / 512), var = sq * (1.f / 512) - mu * mu;
  float inv = rsqrtf(var + 1e-5f);
  float2 gg = *(const float2*)&g[t * 2], bb = *(const float2*)&bta[t * 2];
  float o0 = (x0 - mu) * inv * gg.x + bb.x;
  float o1 = (x1 - mu) * inv * gg.y + bb.y;
  short h0, l0, h1, l1;
  split_trunc(o0, h0, l0);
  split_trunc(o1, h1, l1);
  *(uint32_t*)&hi[idx] = (uint32_t)(uint16_t)h0 | ((uint32_t)(uint16_t)h1 << 16);
  *(uint32_t*)&lo[idx] = (uint32_t)(uint16_t)l0 | ((uint32_t)(uint16_t)l1 << 16);
}

// fused KV post: [0,4096) K rne bf16 [b][m][d]; [4096,8192) V -> VT rne bf16 [b][d][m]
__global__ void kv_post_kernel(const float* __restrict__ KV1, const float* __restrict__ KV2,
                               short* __restrict__ khi, short* __restrict__ vt) {
  const int blk = blockIdx.x;
  if (blk < 4096) {
    int t = blk * 256 + threadIdx.x;
    int b = t >> 17, i = t & 131071;
    size_t idx = ((size_t)b * 256 + (i >> 9)) * 1024 + (i & 511);
    khi[t] = (short)bfrne(KV1[idx] + KV2[idx]);
  } else {
    int t = (blk - 4096) * 256 + threadIdx.x;
    int b = t >> 17, i = t & 131071;
    int d = i >> 11, m = i & 2047;
    size_t idx = ((size_t)b * 256 + (m >> 3)) * 1024 + 512 + (m & 7) * 64 + d;
    vt[t] = (short)bfrne(KV1[idx] + KV2[idx]);
  }
}

// ---------- bf16 GEMM: 64x128 tile, 4 waves, BK=32; PASSES=3 (hi/lo x3) or 1 ----------
// OMODE 0: f32 out (+bias).  OMODE 1: rne bf16 out, scaled by oscale.
template <bool GATHER, int OMODE, int PASSES>
__global__ __launch_bounds__(256) void gemm_x3(
    const short* __restrict__ Ahi, const short* __restrict__ Alo,
    const short* __restrict__ BThi, const short* __restrict__ BTlo,
    const float* __restrict__ bias, float* __restrict__ C,
    short* __restrict__ Chi, float oscale,
    int M, int N, int lda, int ldb, int klen) {
  constexpr int NB = (PASSES == 3) ? 2 : 1;
  __shared__ short ldsA[NB][4][64][8];
  __shared__ short ldsB[NB][4][128][8];
  const int tid = threadIdx.x, lane = tid & 63, wave = tid >> 6;
  const int g = lane >> 4, qi = lane & 15;
  const int row0 = blockIdx.x * 64, col0 = blockIdx.y * 128;
  const int kz = blockIdx.z * klen;
  float* Cz = C + (size_t)blockIdx.z * M * N;
  const bool dobias = (blockIdx.z == 0);
  f32x4 acc[4][2] = {};
  const int arow = tid & 63, akg = tid >> 6;
  const int bsm = tid & 127, bk2 = (tid >> 7) * 2;

  for (int k0 = kz; k0 < kz + klen; k0 += 32) {
    __syncthreads();
    size_t ao;
    if (GATHER) {
      int row = row0 + arow;
      int bi = row >> 8, p = row & 255;
      int col = k0 + akg * 8;
      int seg = col >> 9, cc = col & 511;
      int n = (2 * (p >> 4) + (seg >> 1)) * 32 + 2 * (p & 15) + (seg & 1);
      ao = ((size_t)bi * 1024 + n) * 512 + cc;
    } else {
      ao = (size_t)(row0 + arow) * lda + k0 + akg * 8;
    }
    gload16(&Ahi[ao], &ldsA[0][akg][arow][0]);
    if (PASSES == 3) gload16(&Alo[ao], &ldsA[NB - 1][akg][arow][0]);
#pragma unroll
    for (int c = 0; c < 2; ++c) {
      size_t bo = (size_t)(col0 + bsm) * ldb + k0 + (bk2 + c) * 8;
      gload16(&BThi[bo], &ldsB[0][bk2 + c][bsm][0]);
      if (PASSES == 3) gload16(&BTlo[bo], &ldsB[NB - 1][bk2 + c][bsm][0]);
    }
    __syncthreads();
    short8 ah[4], al[4], bh[2], bl[2];
#pragma unroll
    for (int i = 0; i < 4; ++i) {
      ah[i] = *(const short8*)&ldsA[0][g][i * 16 + qi][0];
      if (PASSES == 3) al[i] = *(const short8*)&ldsA[NB - 1][g][i * 16 + qi][0];
    }
#pragma unroll
    for (int j = 0; j < 2; ++j) {
      bh[j] = *(const short8*)&ldsB[0][g][wave * 32 + j * 16 + qi][0];
      if (PASSES == 3) bl[j] = *(const short8*)&ldsB[NB - 1][g][wave * 32 + j * 16 + qi][0];
    }
#pragma unroll
    for (int i = 0; i < 4; ++i)
#pragma unroll
      for (int j = 0; j < 2; ++j) {
        acc[i][j] = MFMA(ah[i], bh[j], acc[i][j]);
        if (PASSES == 3) {
          acc[i][j] = MFMA(al[i], bh[j], acc[i][j]);
          acc[i][j] = MFMA(ah[i], bl[j], acc[i][j]);
        }
      }
  }
#pragma unroll
  for (int i = 0; i < 4; ++i)
#pragma unroll
    for (int j = 0; j < 2; ++j) {
      int colb = col0 + wave * 32 + j * 16 + qi;
      float bs = dobias ? bias[colb] : 0.f;
#pragma unroll
      for (int r = 0; r < 4; ++r) {
        int row = row0 + i * 16 + g * 4 + r;
        if (OMODE == 0) {
          Cz[(size_t)row * N + colb] = acc[i][j][r] + bs;
        } else {
          Chi[(size_t)row * N + colb] = (short)bfrne((acc[i][j][r] + bs) * oscale);
        }
      }
    }
}

// ---------- MFMA flash attention: single-bf16 QK & P, 32 q/wave, K dbuf, exp2 ----------
__global__ __launch_bounds__(256, 2) void attn_kernel(
    const short* __restrict__ Qhi, const short* __restrict__ Khi,
    const short* __restrict__ VT, short* __restrict__ Ohi) {
  __shared__ short Ks[2][4096];      // [dbuf][64x64 swizzled] 16KB
  __shared__ short Ps[4][2][1024];   // [wave][qc] 16KB
  const int tid = threadIdx.x, lane = tid & 63, wave = tid >> 6;
  const int g = lane >> 4, qi = lane & 15;
  const int h = blockIdx.y, b = blockIdx.z;
  const int n0 = blockIdx.x * 128 + wave * 32;

  // Q frags: pre-split & pre-scaled by (0.125*log2e) in the Q-GEMM epilogue
  short8 qh[2][2];   // [qc][ks]
#pragma unroll
  for (int qc = 0; qc < 2; ++qc) {
    const size_t qrow = ((size_t)b * 1024 + n0 + qc * 16 + qi) * 512 + h * 64;
#pragma unroll
    for (int ks = 0; ks < 2; ++ks)
      qh[qc][ks] = *(const short8*)&Qhi[qrow + (ks * 4 + g) * 8];
  }
  float m_run = 0.f, l_run[2] = {0.f, 0.f};
  f32x4 oacc[2][4] = {};
  const short* Kh = Khi + (size_t)b * 2048 * 64;
  const short* Vb = VT + (size_t)b * 64 * 2048;
  const int swz = (qi & 7) << 1;
  const int srow = tid >> 3, sch = tid & 7;
  const int ssw = (sch * 16) ^ ((srow & 7) << 4);
  const int srow2 = (256 + tid) >> 3, ssw2 = (sch * 16) ^ ((srow2 & 7) << 4);

  gload16((const short*)((const char*)Kh + (size_t)srow * 128 + ssw), &Ks[0][tid * 8]);
  gload16((const short*)((const char*)Kh + (size_t)srow2 * 128 + ssw2), &Ks[0][(256 + tid) * 8]);
  __syncthreads();
  int bb = 0;

  for (int t = 0; t < 32; ++t) {
    const int m0 = t * 64;
    if (t < 31) {
      gload16((const short*)((const char*)Kh + (size_t)(m0 + 64 + srow) * 128 + ssw),
              &Ks[bb ^ 1][tid * 8]);
      gload16((const short*)((const char*)Kh + (size_t)(m0 + 64 + srow2) * 128 + ssw2),
              &Ks[bb ^ 1][(256 + tid) * 8]);
    }
    short8 vreg[8];
#pragma unroll
    for (int ks2 = 0; ks2 < 2; ++ks2)
#pragma unroll
      for (int df = 0; df < 4; ++df)
        vreg[ks2 * 4 + df] =
            *(const short8*)&Vb[(size_t)(df * 16 + qi) * 2048 + m0 + ks2 * 32 + g * 8];
    // QK^T swapped (S^T in log2 domain), single bf16
    f32x4 s[2][4] = {};
    const int c0 = 8 * (g ^ (qi & 7)), c1 = 8 * ((g + 4) ^ (qi & 7));
#pragma unroll
    for (int mf = 0; mf < 4; ++mf) {
      const int rowb = (mf * 16 + qi) * 64;
      short8 kh0 = *(const short8*)&Ks[bb][rowb + c0];
      short8 kh1 = *(const short8*)&Ks[bb][rowb + c1];
#pragma unroll
      for (int qc = 0; qc < 2; ++qc) {
        s[qc][mf] = MFMA(kh0, qh[qc][0], s[qc][mf]);
        s[qc][mf] = MFMA(kh1, qh[qc][1], s[qc][mf]);
      }
    }
    // defer-max online softmax (log2 units)
    float lmax = s[0][0][0];
#pragma unroll
    for (int qc = 0; qc < 2; ++qc)
#pragma unroll
      for (int mf = 0; mf < 4; ++mf)
#pragma unroll
        for (int r = 0; r < 4; ++r) lmax = fmaxf(lmax, s[qc][mf][r]);
    if (!__all(lmax <= m_run + 43.f)) {
      float mx = lmax;
#pragma unroll
      for (int off = 1; off < 64; off <<= 1) mx = fmaxf(mx, __shfl_xor(mx, off));
      float cf = exp2f(m_run - mx);
      l_run[0] *= cf; l_run[1] *= cf;
#pragma unroll
      for (int qc = 0; qc < 2; ++qc)
#pragma unroll
        for (int df = 0; df < 4; ++df) oacc[qc][df] *= cf;
      m_run = mx;
    }
    // exp2, truncate to bf16; accumulate l from the TRUNCATED values (bias cancels)
#pragma unroll
    for (int qc = 0; qc < 2; ++qc) {
      float lsum = 0.f;
#pragma unroll
      for (int mf = 0; mf < 4; ++mf)
#pragma unroll
        for (int r = 0; r < 4; ++r) {
          float p = exp2f(s[qc][mf][r] - m_run);
          uint32_t u = __float_as_uint(p);
          s[qc][mf][r] = p;
          lsum += __uint_as_float(u & 0xffff0000u);
        }
      lsum += __shfl_xor(lsum, 16);
      lsum += __shfl_xor(lsum, 32);
      l_run[qc] += lsum;
    }
    // pack P (trunc hi only) -> per-wave-per-qc LDS bounce, then PV
#pragma unroll
    for (int qc = 0; qc < 2; ++qc) {
#pragma unroll
      for (int mf = 0; mf < 4; ++mf) {
        uint32_t u0 = __float_as_uint(s[qc][mf][0]);
        uint32_t u1 = __float_as_uint(s[qc][mf][1]);
        uint32_t u2 = __float_as_uint(s[qc][mf][2]);
        uint32_t u3 = __float_as_uint(s[qc][mf][3]);
        uint2 hp;
        hp.x = (u0 >> 16) | (u1 & 0xffff0000u);
        hp.y = (u2 >> 16) | (u3 & 0xffff0000u);
        int uw = ((mf * 4 + g) ^ swz) << 2;
        *(uint2*)&Ps[wave][qc][qi * 64 + uw] = hp;
      }
#pragma unroll
      for (int ks2 = 0; ks2 < 2; ++ks2) {
        int ur = ((ks2 * 8 + g * 2) ^ swz) << 2;
        short8 pa = *(const short8*)&Ps[wave][qc][qi * 64 + ur];
#pragma unroll
        for (int df = 0; df < 4; ++df)
          oacc[qc][df] = MFMA(vreg[ks2 * 4 + df], pa, oacc[qc][df]);
      }
    }
    __syncthreads();
    bb ^= 1;
  }
  // epilogue: divide by l, RNE bf16 (unbiased -> no systematic proj error)
#pragma unroll
  for (int qc = 0; qc < 2; ++qc) {
    float linv = 1.f / l_run[qc];
    size_t obase = ((size_t)b * 1024 + n0 + qc * 16 + qi) * 512 + h * 64;
#pragma unroll
    for (int df = 0; df < 4; ++df) {
      float o0 = oacc[qc][df][0] * linv, o1 = oacc[qc][df][1] * linv;
      float o2 = oacc[qc][df][2] * linv, o3 = oacc[qc][df][3] * linv;
      uint2 hp;
      hp.x = bfrne(o0) | (bfrne(o1) << 16);
      hp.y = bfrne(o2) | (bfrne(o3) << 16);
      *(uint2*)&Ohi[obase + df * 16 + g * 4] = hp;
    }
  }
}

// ---------- launcher ----------
extern "C" void kernel_launch(void* const* d_in, const int* in_sizes, int n_in,
                              void* d_out, int out_size, void* d_ws, size_t ws_size,
                              hipStream_t stream) {
  const float* x      = (const float*)d_in[0];
  const float* q_w    = (const float*)d_in[3];
  const float* q_b    = (const float*)d_in[4];
  const float* kv_w   = (const float*)d_in[5];
  const float* kv_b   = (const float*)d_in[6];
  const float* sr_w   = (const float*)d_in[7];
  const float* sr_b   = (const float*)d_in[8];
  const float* ln_g   = (const float*)d_in[9];
  const float* ln_b   = (const float*)d_in[10];
  const float* proj_w = (const float*)d_in[11];
  const float* proj_b = (const float*)d_in[12];

  char* W = (char*)d_ws;
  const size_t MB = 1024 * 1024;
  short* xhi   = (short*)(W);                  // 0-8
  short* xlo   = (short*)(W + 8 * MB);         // 8-16
  short* WcThi = (short*)(W + 16 * MB);        // 16-18
  short* WcTlo = (short*)(W + 18 * MB);        // 18-20
  float* Cbuf  = (float*)(W + 20 * MB);        // 20-36 (4 partials x 4MB)
  short* LNhi  = (short*)(W + 36 * MB);        // 36-38
  short* LNlo  = (short*)(W + 38 * MB);        // 38-40
  short* kvThi = (short*)(W + 40 * MB);        // 40-41
  short* kvTlo = (short*)(W + 41 * MB);        // 41-42
  short* qThi  = (short*)(W + 42 * MB);        // 42-42.5
  short* pThi  = (short*)(W + 43 * MB);        // 43-43.5
  float* KVp   = (float*)(W + 20 * MB);        // 20-36 (Cbuf dead)
  short* Khi   = (short*)(W + 36 * MB);        // 36-38 (LN dead)
  short* VTb   = (short*)(W + 16 * MB);        // 16-18 (WcT dead)
  short* Qhi   = (short*)(W + 20 * MB);        // 20-28 (KVp dead)
  short* Ohi   = (short*)(W + 28 * MB);        // 28-36

  prep_weights_kernel<<<5120, 256, 0, stream>>>(
      sr_w, kv_w, q_w, proj_w, WcThi, WcTlo, kvThi, kvTlo, qThi, pThi);
  split_x_kernel<<<2048, 256, 0, stream>>>(x, xhi, xlo);
  gemm_x3<true, 0, 3><<<dim3(32, 4, 4), 256, 0, stream>>>(
      xhi, xlo, WcThi, WcTlo, sr_b, Cbuf, nullptr, 1.f,
      2048, 512, 512, 2048, 512);
  ln_split_kernel<<<2048, 256, 0, stream>>>(Cbuf, ln_g, ln_b, LNhi, LNlo);
  gemm_x3<false, 0, 3><<<dim3(32, 8, 2), 256, 0, stream>>>(
      LNhi, LNlo, kvThi, kvTlo, kv_b, KVp, nullptr, 1.f,
      2048, 1024, 512, 512, 256);
  kv_post_kernel<<<8192, 256, 0, stream>>>(KVp, KVp + (size_t)2 * MB, Khi, VTb);
  gemm_x3<false, 1, 1><<<dim3(128, 4, 1), 256, 0, stream>>>(
      xhi, nullptr, qThi, nullptr, q_b, nullptr, Qhi, 0.125f * 1.44269504f,
      8192, 512, 512, 512, 512);
  attn_kernel<<<dim3(8, 8, 8), 256, 0, stream>>>(Qhi, Khi, VTb, Ohi);
  gemm_x3<false, 0, 1><<<dim3(128, 4, 1), 256, 0, stream>>>(
      Ohi, nullptr, pThi, nullptr, proj_b, (float*)d_out, nullptr, 1.f,
      8192, 512, 512, 512, 512);
}

// Round 8
// 202.157 us; speedup vs baseline: 1.3679x; 1.0115x over previous
//
#include <hip/hip_runtime.h>
#include <hip/hip_bf16.h>
#include <stdint.h>

typedef __attribute__((ext_vector_type(8))) short short8;
typedef __attribute__((ext_vector_type(4))) float f32x4;

#define MFMA(A, B, C) __builtin_amdgcn_mfma_f32_16x16x32_bf16(A, B, C, 0, 0, 0)

__device__ inline void split_trunc(float f, short& hi, short& lo) {
  uint32_t u = __float_as_uint(f);
  hi = (short)(u >> 16);
  float r = f - __uint_as_float(u & 0xffff0000u);
  lo = (short)(__float_as_uint(r) >> 16);
}

__device__ inline uint32_t bfrne(float f) {   // RNE bf16, as low 16 bits
  uint32_t u = __float_as_uint(f);
  return (u + 0x7FFFu + ((u >> 16) & 1u)) >> 16;
}

// packed RNE pair via compiler (lowers to v_cvt_pk_bf16_f32; do NOT hand-write asm — m240)
__device__ inline uint32_t pkrne(float a, float b) {
  union { __hip_bfloat162 v; uint32_t u; } c;
  c.v.x = __float2bfloat16(a);
  c.v.y = __float2bfloat16(b);
  return c.u;
}

__device__ inline void gload16(const short* g, short* l) {
  __builtin_amdgcn_global_load_lds(
      (const __attribute__((address_space(1))) void*)g,
      (__attribute__((address_space(3))) void*)l, 16, 0, 0);
}

// ---------- fused prep: weights + x split ----------
// [0,4096) wct split; [4096,4608) kv_w T split; [4608,4864) q_w T rne;
// [4864,5120) proj_w T rne; [5120,7168) x trunc-split
__global__ __launch_bounds__(256) void prep_all_kernel(
    const float* __restrict__ sr_w, const float* __restrict__ kv_w,
    const float* __restrict__ q_w, const float* __restrict__ proj_w,
    const float* __restrict__ x,
    short* __restrict__ WcThi, short* __restrict__ WcTlo,
    short* __restrict__ kvThi, short* __restrict__ kvTlo,
    short* __restrict__ qThi, short* __restrict__ pThi,
    short* __restrict__ xhi, short* __restrict__ xlo) {
  __shared__ float tile[32][33];
  const int blk = blockIdx.x;
  if (blk < 4096) {
    int t = blk * 256 + threadIdx.x;
    int kk = t & 2047, o = t >> 11;
    float v = sr_w[(size_t)o * 2048 + ((kk & 511) << 2) + (kk >> 9)];
    short a, b; split_trunc(v, a, b);
    WcThi[t] = a; WcTlo[t] = b;
    return;
  }
  if (blk >= 5120) {
    int t = (blk - 5120) * 256 + threadIdx.x;
    float4 v0 = *(const float4*)&x[(size_t)t * 8];
    float4 v1 = *(const float4*)&x[(size_t)t * 8 + 4];
    float buf[8] = {v0.x, v0.y, v0.z, v0.w, v1.x, v1.y, v1.z, v1.w};
    short8 h, l;
#pragma unroll
    for (int i = 0; i < 8; ++i) { short a, b; split_trunc(buf[i], a, b); h[i] = a; l[i] = b; }
    *(short8*)&xhi[(size_t)t * 8] = h;
    *(short8*)&xlo[(size_t)t * 8] = l;
    return;
  }
  const float* in; short* ohi; short* olo; int N, bx, by; bool dosplit;
  if (blk < 4608) {
    in = kv_w; ohi = kvThi; olo = kvTlo; N = 1024; dosplit = true;
    int i = blk - 4096; bx = i & 31; by = i >> 5;
  } else if (blk < 4864) {
    in = q_w; ohi = qThi; olo = nullptr; N = 512; dosplit = false;
    int i = blk - 4608; bx = i & 15; by = i >> 4;
  } else {
    in = proj_w; ohi = pThi; olo = nullptr; N = 512; dosplit = false;
    int i = blk - 4864; bx = i & 15; by = i >> 4;
  }
  const int K = 512;
  const int tx = threadIdx.x & 31, ty = threadIdx.x >> 5;
#pragma unroll
  for (int i = 0; i < 4; ++i)
    tile[ty + i * 8][tx] = in[(size_t)(by * 32 + ty + i * 8) * N + bx * 32 + tx];
  __syncthreads();
#pragma unroll
  for (int i = 0; i < 4; ++i) {
    int n = bx * 32 + ty + i * 8;
    float v = tile[tx][ty + i * 8];
    size_t idx = (size_t)n * K + by * 32 + tx;
    if (dosplit) {
      short a, b; split_trunc(v, a, b);
      ohi[idx] = a; olo[idx] = b;
    } else {
      ohi[idx] = (short)bfrne(v);
    }
  }
}

__global__ __launch_bounds__(256) void ln_split_kernel(
    const float* __restrict__ X, const float* __restrict__ g,
    const float* __restrict__ bta, short* __restrict__ hi, short* __restrict__ lo) {
  const int row = blockIdx.x, t = threadIdx.x;
  size_t idx = (size_t)row * 512 + t * 2;
  const size_t PS = (size_t)2048 * 512;
  float2 a0 = *(const float2*)&X[idx];
  float2 a1 = *(const float2*)&X[idx + PS];
  float2 a2 = *(const float2*)&X[idx + 2 * PS];
  float2 a3 = *(const float2*)&X[idx + 3 * PS];
  float x0 = a0.x + a1.x + a2.x + a3.x;
  float x1 = a0.y + a1.y + a2.y + a3.y;
  float s = x0 + x1, sq = x0 * x0 + x1 * x1;
#pragma unroll
  for (int off = 1; off < 64; off <<= 1) {
    s += __shfl_xor(s, off);
    sq += __shfl_xor(sq, off);
  }
  __shared__ float rs[4], rq[4];
  int wid = t >> 6;
  if ((t & 63) == 0) { rs[wid] = s; rq[wid] = sq; }
  __syncthreads();
  s = rs[0] + rs[1] + rs[2] + rs[3];
  sq = rq[0] + rq[1] + rq[2] + rq[3];
  float mu = s * (1.f / 512), var = sq * (1.f / 512) - mu * mu;
  float inv = rsqrtf(var + 1e-5f);
  float2 gg = *(const float2*)&g[t * 2], bb = *(const float2*)&bta[t * 2];
  float o0 = (x0 - mu) * inv * gg.x + bb.x;
  float o1 = (x1 - mu) * inv * gg.y + bb.y;
  short h0, l0, h1, l1;
  split_trunc(o0, h0, l0);
  split_trunc(o1, h1, l1);
  *(uint32_t*)&hi[idx] = (uint32_t)(uint16_t)h0 | ((uint32_t)(uint16_t)h1 << 16);
  *(uint32_t*)&lo[idx] = (uint32_t)(uint16_t)l0 | ((uint32_t)(uint16_t)l1 << 16);
}

// fused KV post: [0,4096) K rne bf16 [b][m][d]; [4096,8192) V -> VT rne bf16 [b][d][m]
__global__ void kv_post_kernel(const float* __restrict__ KV1, const float* __restrict__ KV2,
                               short* __restrict__ khi, short* __restrict__ vt) {
  const int blk = blockIdx.x;
  if (blk < 4096) {
    int t = blk * 256 + threadIdx.x;
    int b = t >> 17, i = t & 131071;
    size_t idx = ((size_t)b * 256 + (i >> 9)) * 1024 + (i & 511);
    khi[t] = (short)bfrne(KV1[idx] + KV2[idx]);
  } else {
    int t = (blk - 4096) * 256 + threadIdx.x;
    int b = t >> 17, i = t & 131071;
    int d = i >> 11, m = i & 2047;
    size_t idx = ((size_t)b * 256 + (m >> 3)) * 1024 + 512 + (m & 7) * 64 + d;
    vt[t] = (short)bfrne(KV1[idx] + KV2[idx]);
  }
}

// ---------- bf16 GEMM: 64x128 tile, 4 waves, BK=32; PASSES=3 or 1 ----------
template <bool GATHER, int OMODE, int PASSES>
__global__ __launch_bounds__(256) void gemm_x3(
    const short* __restrict__ Ahi, const short* __restrict__ Alo,
    const short* __restrict__ BThi, const short* __restrict__ BTlo,
    const float* __restrict__ bias, float* __restrict__ C,
    short* __restrict__ Chi, float oscale,
    int M, int N, int lda, int ldb, int klen) {
  constexpr int NB = (PASSES == 3) ? 2 : 1;
  __shared__ short ldsA[NB][4][64][8];
  __shared__ short ldsB[NB][4][128][8];
  const int tid = threadIdx.x, lane = tid & 63, wave = tid >> 6;
  const int g = lane >> 4, qi = lane & 15;
  const int row0 = blockIdx.x * 64, col0 = blockIdx.y * 128;
  const int kz = blockIdx.z * klen;
  float* Cz = C + (size_t)blockIdx.z * M * N;
  const bool dobias = (blockIdx.z == 0);
  f32x4 acc[4][2] = {};
  const int arow = tid & 63, akg = tid >> 6;
  const int bsm = tid & 127, bk2 = (tid >> 7) * 2;

  for (int k0 = kz; k0 < kz + klen; k0 += 32) {
    __syncthreads();
    size_t ao;
    if (GATHER) {
      int row = row0 + arow;
      int bi = row >> 8, p = row & 255;
      int col = k0 + akg * 8;
      int seg = col >> 9, cc = col & 511;
      int n = (2 * (p >> 4) + (seg >> 1)) * 32 + 2 * (p & 15) + (seg & 1);
      ao = ((size_t)bi * 1024 + n) * 512 + cc;
    } else {
      ao = (size_t)(row0 + arow) * lda + k0 + akg * 8;
    }
    gload16(&Ahi[ao], &ldsA[0][akg][arow][0]);
    if (PASSES == 3) gload16(&Alo[ao], &ldsA[NB - 1][akg][arow][0]);
#pragma unroll
    for (int c = 0; c < 2; ++c) {
      size_t bo = (size_t)(col0 + bsm) * ldb + k0 + (bk2 + c) * 8;
      gload16(&BThi[bo], &ldsB[0][bk2 + c][bsm][0]);
      if (PASSES == 3) gload16(&BTlo[bo], &ldsB[NB - 1][bk2 + c][bsm][0]);
    }
    __syncthreads();
    short8 ah[4], al[4], bh[2], bl[2];
#pragma unroll
    for (int i = 0; i < 4; ++i) {
      ah[i] = *(const short8*)&ldsA[0][g][i * 16 + qi][0];
      if (PASSES == 3) al[i] = *(const short8*)&ldsA[NB - 1][g][i * 16 + qi][0];
    }
#pragma unroll
    for (int j = 0; j < 2; ++j) {
      bh[j] = *(const short8*)&ldsB[0][g][wave * 32 + j * 16 + qi][0];
      if (PASSES == 3) bl[j] = *(const short8*)&ldsB[NB - 1][g][wave * 32 + j * 16 + qi][0];
    }
#pragma unroll
    for (int i = 0; i < 4; ++i)
#pragma unroll
      for (int j = 0; j < 2; ++j) {
        acc[i][j] = MFMA(ah[i], bh[j], acc[i][j]);
        if (PASSES == 3) {
          acc[i][j] = MFMA(al[i], bh[j], acc[i][j]);
          acc[i][j] = MFMA(ah[i], bl[j], acc[i][j]);
        }
      }
  }
#pragma unroll
  for (int i = 0; i < 4; ++i)
#pragma unroll
    for (int j = 0; j < 2; ++j) {
      int colb = col0 + wave * 32 + j * 16 + qi;
      float bs = dobias ? bias[colb] : 0.f;
#pragma unroll
      for (int r = 0; r < 4; ++r) {
        int row = row0 + i * 16 + g * 4 + r;
        if (OMODE == 0) {
          Cz[(size_t)row * N + colb] = acc[i][j][r] + bs;
        } else {
          Chi[(size_t)row * N + colb] = (short)bfrne((acc[i][j][r] + bs) * oscale);
        }
      }
    }
}

// ---------- MFMA flash attention: single-bf16 QK & P, 32 q/wave, K dbuf, exp2 ----------
// VALU trims: -m_run folded into MFMA C-init; max3 tree; compiler cvt_pk; setprio.
__global__ __launch_bounds__(256, 2) void attn_kernel(
    const short* __restrict__ Qhi, const short* __restrict__ Khi,
    const short* __restrict__ VT, short* __restrict__ Ohi) {
  __shared__ short Ks[2][4096];      // [dbuf][64x64 swizzled] 16KB
  __shared__ short Ps[4][2][1024];   // [wave][qc] 16KB
  const int tid = threadIdx.x, lane = tid & 63, wave = tid >> 6;
  const int g = lane >> 4, qi = lane & 15;
  const int h = blockIdx.y, b = blockIdx.z;
  const int n0 = blockIdx.x * 128 + wave * 32;

  short8 qh[2][2];   // [qc][ks]
#pragma unroll
  for (int qc = 0; qc < 2; ++qc) {
    const size_t qrow = ((size_t)b * 1024 + n0 + qc * 16 + qi) * 512 + h * 64;
#pragma unroll
    for (int ks = 0; ks < 2; ++ks)
      qh[qc][ks] = *(const short8*)&Qhi[qrow + (ks * 4 + g) * 8];
  }
  float m_run = 0.f, l_run[2] = {0.f, 0.f};
  f32x4 oacc[2][4] = {};
  const short* Kh = Khi + (size_t)b * 2048 * 64;
  const short* Vb = VT + (size_t)b * 64 * 2048;
  const int swz = (qi & 7) << 1;
  const int srow = tid >> 3, sch = tid & 7;
  const int ssw = (sch * 16) ^ ((srow & 7) << 4);
  const int srow2 = (256 + tid) >> 3, ssw2 = (sch * 16) ^ ((srow2 & 7) << 4);

  gload16((const short*)((const char*)Kh + (size_t)srow * 128 + ssw), &Ks[0][tid * 8]);
  gload16((const short*)((const char*)Kh + (size_t)srow2 * 128 + ssw2), &Ks[0][(256 + tid) * 8]);
  __syncthreads();
  int bb = 0;

  for (int t = 0; t < 32; ++t) {
    const int m0 = t * 64;
    if (t < 31) {
      gload16((const short*)((const char*)Kh + (size_t)(m0 + 64 + srow) * 128 + ssw),
              &Ks[bb ^ 1][tid * 8]);
      gload16((const short*)((const char*)Kh + (size_t)(m0 + 64 + srow2) * 128 + ssw2),
              &Ks[bb ^ 1][(256 + tid) * 8]);
    }
    short8 vreg[8];
#pragma unroll
    for (int ks2 = 0; ks2 < 2; ++ks2)
#pragma unroll
      for (int df = 0; df < 4; ++df)
        vreg[ks2 * 4 + df] =
            *(const short8*)&Vb[(size_t)(df * 16 + qi) * 2048 + m0 + ks2 * 32 + g * 8];
    // QK^T swapped, S^T in log2 domain, C-init = -m_run (folds the max shift)
    const f32x4 minit = {-m_run, -m_run, -m_run, -m_run};
    f32x4 s[2][4];
    const int c0 = 8 * (g ^ (qi & 7)), c1 = 8 * ((g + 4) ^ (qi & 7));
    __builtin_amdgcn_s_setprio(1);
#pragma unroll
    for (int mf = 0; mf < 4; ++mf) {
      const int rowb = (mf * 16 + qi) * 64;
      short8 kh0 = *(const short8*)&Ks[bb][rowb + c0];
      short8 kh1 = *(const short8*)&Ks[bb][rowb + c1];
#pragma unroll
      for (int qc = 0; qc < 2; ++qc) {
        s[qc][mf] = MFMA(kh0, qh[qc][0], minit);
        s[qc][mf] = MFMA(kh1, qh[qc][1], s[qc][mf]);
      }
    }
    __builtin_amdgcn_s_setprio(0);
    // defer-max check (s is already relative to m_run); max3-friendly tree
    float gm[8];
#pragma unroll
    for (int qc = 0; qc < 2; ++qc)
#pragma unroll
      for (int mf = 0; mf < 4; ++mf)
        gm[qc * 4 + mf] = fmaxf(fmaxf(fmaxf(s[qc][mf][0], s[qc][mf][1]), s[qc][mf][2]),
                                s[qc][mf][3]);
    float lmax = fmaxf(fmaxf(fmaxf(gm[0], gm[1]), fmaxf(gm[2], gm[3])),
                       fmaxf(fmaxf(gm[4], gm[5]), fmaxf(gm[6], gm[7])));
    if (!__all(lmax <= 43.f)) {
      float mx = lmax;
#pragma unroll
      for (int off = 1; off < 64; off <<= 1) mx = fmaxf(mx, __shfl_xor(mx, off));
      float cf = exp2f(-mx);
      l_run[0] *= cf; l_run[1] *= cf;
#pragma unroll
      for (int qc = 0; qc < 2; ++qc)
#pragma unroll
        for (int df = 0; df < 4; ++df) oacc[qc][df] *= cf;
      m_run += mx;
#pragma unroll
      for (int qc = 0; qc < 2; ++qc)
#pragma unroll
        for (int mf = 0; mf < 4; ++mf)
#pragma unroll
          for (int r = 0; r < 4; ++r) s[qc][mf][r] -= mx;
    }
    // exp2 -> packed RNE bf16 (compiler cvt_pk); lsum from the SAME rounded values
#pragma unroll
    for (int qc = 0; qc < 2; ++qc) {
      float lsum = 0.f;
#pragma unroll
      for (int mf = 0; mf < 4; ++mf) {
        float p0 = exp2f(s[qc][mf][0]);
        float p1 = exp2f(s[qc][mf][1]);
        float p2 = exp2f(s[qc][mf][2]);
        float p3 = exp2f(s[qc][mf][3]);
        uint32_t h01 = pkrne(p0, p1);
        uint32_t h23 = pkrne(p2, p3);
        lsum += __uint_as_float(h01 << 16) + __uint_as_float(h01 & 0xffff0000u);
        lsum += __uint_as_float(h23 << 16) + __uint_as_float(h23 & 0xffff0000u);
        uint2 hp; hp.x = h01; hp.y = h23;
        int uw = ((mf * 4 + g) ^ swz) << 2;
        *(uint2*)&Ps[wave][qc][qi * 64 + uw] = hp;
      }
      lsum += __shfl_xor(lsum, 16);
      lsum += __shfl_xor(lsum, 32);
      l_run[qc] += lsum;
    }
    // PV
#pragma unroll
    for (int qc = 0; qc < 2; ++qc) {
#pragma unroll
      for (int ks2 = 0; ks2 < 2; ++ks2) {
        int ur = ((ks2 * 8 + g * 2) ^ swz) << 2;
        short8 pa = *(const short8*)&Ps[wave][qc][qi * 64 + ur];
        __builtin_amdgcn_s_setprio(1);
#pragma unroll
        for (int df = 0; df < 4; ++df)
          oacc[qc][df] = MFMA(vreg[ks2 * 4 + df], pa, oacc[qc][df]);
        __builtin_amdgcn_s_setprio(0);
      }
    }
    __syncthreads();
    bb ^= 1;
  }
  // epilogue: divide by l, RNE bf16
#pragma unroll
  for (int qc = 0; qc < 2; ++qc) {
    float linv = 1.f / l_run[qc];
    size_t obase = ((size_t)b * 1024 + n0 + qc * 16 + qi) * 512 + h * 64;
#pragma unroll
    for (int df = 0; df < 4; ++df) {
      float o0 = oacc[qc][df][0] * linv, o1 = oacc[qc][df][1] * linv;
      float o2 = oacc[qc][df][2] * linv, o3 = oacc[qc][df][3] * linv;
      uint2 hp;
      hp.x = pkrne(o0, o1);
      hp.y = pkrne(o2, o3);
      *(uint2*)&Ohi[obase + df * 16 + g * 4] = hp;
    }
  }
}

// ---------- launcher ----------
extern "C" void kernel_launch(void* const* d_in, const int* in_sizes, int n_in,
                              void* d_out, int out_size, void* d_ws, size_t ws_size,
                              hipStream_t stream) {
  const float* x      = (const float*)d_in[0];
  const float* q_w    = (const float*)d_in[3];
  const float* q_b    = (const float*)d_in[4];
  const float* kv_w   = (const float*)d_in[5];
  const float* kv_b   = (const float*)d_in[6];
  const float* sr_w   = (const float*)d_in[7];
  const float* sr_b   = (const float*)d_in[8];
  const float* ln_g   = (const float*)d_in[9];
  const float* ln_b   = (const float*)d_in[10];
  const float* proj_w = (const float*)d_in[11];
  const float* proj_b = (const float*)d_in[12];

  char* W = (char*)d_ws;
  const size_t MB = 1024 * 1024;
  short* xhi   = (short*)(W);                  // 0-8
  short* xlo   = (short*)(W + 8 * MB);         // 8-16
  short* WcThi = (short*)(W + 16 * MB);        // 16-18
  short* WcTlo = (short*)(W + 18 * MB);        // 18-20
  float* Cbuf  = (float*)(W + 20 * MB);        // 20-36 (4 partials x 4MB)
  short* LNhi  = (short*)(W + 36 * MB);        // 36-38
  short* LNlo  = (short*)(W + 38 * MB);        // 38-40
  short* kvThi = (short*)(W + 40 * MB);        // 40-41
  short* kvTlo = (short*)(W + 41 * MB);        // 41-42
  short* qThi  = (short*)(W + 42 * MB);        // 42-42.5
  short* pThi  = (short*)(W + 43 * MB);        // 43-43.5
  float* KVp   = (float*)(W + 20 * MB);        // 20-36 (Cbuf dead)
  short* Khi   = (short*)(W + 36 * MB);        // 36-38 (LN dead)
  short* VTb   = (short*)(W + 16 * MB);        // 16-18 (WcT dead)
  short* Qhi   = (short*)(W + 20 * MB);        // 20-28 (KVp dead)
  short* Ohi   = (short*)(W + 28 * MB);        // 28-36

  prep_all_kernel<<<7168, 256, 0, stream>>>(
      sr_w, kv_w, q_w, proj_w, x, WcThi, WcTlo, kvThi, kvTlo, qThi, pThi, xhi, xlo);
  gemm_x3<true, 0, 3><<<dim3(32, 4, 4), 256, 0, stream>>>(
      xhi, xlo, WcThi, WcTlo, sr_b, Cbuf, nullptr, 1.f,
      2048, 512, 512, 2048, 512);
  ln_split_kernel<<<2048, 256, 0, stream>>>(Cbuf, ln_g, ln_b, LNhi, LNlo);
  gemm_x3<false, 0, 3><<<dim3(32, 8, 2), 256, 0, stream>>>(
      LNhi, LNlo, kvThi, kvTlo, kv_b, KVp, nullptr, 1.f,
      2048, 1024, 512, 512, 256);
  kv_post_kernel<<<8192, 256, 0, stream>>>(KVp, KVp + (size_t)2 * MB, Khi, VTb);
  gemm_x3<false, 1, 1><<<dim3(128, 4, 1), 256, 0, stream>>>(
      xhi, nullptr, qThi, nullptr, q_b, nullptr, Qhi, 0.125f * 1.44269504f,
      8192, 512, 512, 512, 512);
  attn_kernel<<<dim3(8, 8, 8), 256, 0, stream>>>(Qhi, Khi, VTb, Ohi);
  gemm_x3<false, 0, 1><<<dim3(128, 4, 1), 256, 0, stream>>>(
      Ohi, nullptr, pThi, nullptr, proj_b, (float*)d_out, nullptr, 1.f,
      8192, 512, 512, 512, 512);
}